// Round 4
// baseline (74.424 us; speedup 1.0000x reference)
//
#include <hip/hip_runtime.h>

#define N_EP     4096     // 2048 lines * 2 endpoints
#define NLINES   2048
#define KPTS     2048
#define CCH      256
#define HC_      128
#define WC_      128
#define MAXNBR   16
#define NPTS_ALL 6144     // N_EP + KPTS

// ---- output chunk offsets (floats) ----
#define O_PTS  0          // all_points (1,6144,2)       12288
#define O_SC   12288      // all_scores (1,6144)          6144
#define O_DESC 18432      // all_descs (1,256,6144)    1572864
#define O_NL   1591296    // new_lines (1,2048,2,2)       8192
#define O_LJI  1599488    // lines_junc_idx (1,2048,2)    4096
#define O_LS   1603584    // ls (1,2048)                  2048

// ---- ws offsets (4-byte words) ----
#define W_LS   0          // float[2048]
#define W_DEG  2048       // int[4096]
#define W_NBR  6144       // int[4096*16]
#define W_KEEP 71680      // int[2048]
#define W_JUNC 73728      // float[8192] (x,y interleaved)
#define W_NORM 81920      // float[4096]
#define W_V    86016      // float[256*4096] unnormalized junction descs

// ============================================================================
// K_A "front": all input-only work in one launch.
//   blocks [0,4096)        : neighbor lists of the eps<=3 ball graph (1 blk/pt)
//   blocks [4096,6144)     : keypoint suppression (1 blk/kp)
//   block  6144            : ls normalize
//   block  6145            : zero norm accumulator
// ============================================================================
__global__ __launch_bounds__(256) void k_front(
    const float2* __restrict__ ep, const float2* __restrict__ kpts,
    const float* __restrict__ ksc, const float* __restrict__ lsc,
    int* __restrict__ deg, int* __restrict__ nbr, int* __restrict__ keep_ws,
    float* __restrict__ ws_ls, float* __restrict__ norm,
    float* __restrict__ out_pts, float* __restrict__ out_sc,
    float* __restrict__ out_ls) {
    __shared__ float red[256];
    __shared__ int flag;
    int b = blockIdx.x, t = threadIdx.x;

    if (b < N_EP) {                       // ---- neighbor lists ----
        if (t == 0) flag = 0;
        __syncthreads();
        float2 p = ep[b];
        for (int j = t; j < N_EP; j += 256) {
            if (j == b) continue;
            float2 q = ep[j];
            float dx = p.x - q.x, dy = p.y - q.y;
            if (dx * dx + dy * dy <= 9.0f) {
                int s = atomicAdd(&flag, 1);
                if (s < MAXNBR) nbr[b * MAXNBR + s] = j;
            }
        }
        __syncthreads();
        if (t == 0) deg[b] = min(flag, MAXNBR);
    } else if (b < N_EP + KPTS) {         // ---- keypoint suppression ----
        int k = b - N_EP;
        if (t == 0) flag = 0;
        __syncthreads();
        float2 p = kpts[k];
        int hit = 0;
        for (int j = t; j < N_EP; j += 256) {
            float2 q = ep[j];
            float dx = p.x - q.x, dy = p.y - q.y;
            if (dx * dx + dy * dy < 16.0f) hit = 1;
        }
        if (__any(hit) && (t & 63) == 0) atomicOr(&flag, 1);
        __syncthreads();
        if (t == 0) {
            int keep = !flag;
            keep_ws[k] = keep;
            out_pts[2 * (N_EP + k)] = keep ? p.x : 0.f;
            out_pts[2 * (N_EP + k) + 1] = keep ? p.y : 0.f;
            out_sc[N_EP + k] = keep ? ksc[k] : 0.f;
        }
    } else if (b == N_EP + KPTS) {        // ---- ls ----
        float m = -1e30f;
        for (int i = t; i < NLINES; i += 256) m = fmaxf(m, lsc[i]);
        red[t] = m; __syncthreads();
        for (int s = 128; s > 0; s >>= 1) {
            if (t < s) red[t] = fmaxf(red[t], red[t + s]);
            __syncthreads();
        }
        float denom = 1e-8f + red[0];
        for (int i = t; i < NLINES; i += 256) {
            float v = lsc[i] / denom;
            ws_ls[i] = v;
            out_ls[i] = v;
        }
    } else {                              // ---- zero norm ----
        for (int i = t; i < N_EP; i += 256) norm[i] = 0.f;
    }
}

// ============================================================================
// K_B: single-block connected components + dense relabel + ALL junction
// outputs (means, scores, new_lines, lines_junc_idx) via LDS segment sums.
// Dynamic LDS layout (ints): lab[4096] rnk[4096] fcnt[4096] fsx[4096]
//                            fsy[4096] fss[4096] wsum[16]
// ============================================================================
__global__ __launch_bounds__(1024) void k_cluster(
    const float2* __restrict__ ep, const int* __restrict__ deg,
    const int* __restrict__ nbr, const float* __restrict__ ws_ls,
    float* __restrict__ junc, float* __restrict__ out_pts,
    float* __restrict__ out_sc, float* __restrict__ out_nl,
    float* __restrict__ out_lji) {
    extern __shared__ int smem[];
    int*   lab  = smem;
    int*   rnk  = smem + N_EP;
    float* fcnt = (float*)(smem + 2 * N_EP);
    float* fsx  = (float*)(smem + 3 * N_EP);
    float* fsy  = (float*)(smem + 4 * N_EP);
    float* fss  = (float*)(smem + 5 * N_EP);
    int*   wsum = smem + 6 * N_EP;
    __shared__ int changed;

    int t = threadIdx.x;
    for (int i = t; i < N_EP; i += 1024) {
        lab[i] = i;
        fcnt[i] = 0.f; fsx[i] = 0.f; fsy[i] = 0.f; fss[i] = 0.f;
    }
    // min-label propagation with pointer jumping
    for (int it = 0; it < 64; ++it) {
        __syncthreads();
        if (t == 0) changed = 0;
        __syncthreads();
        int f = 0;
        for (int i = t; i < N_EP; i += 1024) {
            int m = lab[i];
            int dg = deg[i];
            const int* nb = nbr + i * MAXNBR;
            for (int q = 0; q < dg; q++) m = min(m, lab[nb[q]]);
            m = min(m, lab[m]);
            if (m < lab[i]) { lab[i] = m; f = 1; }
        }
        if (f) atomicOr(&changed, 1);
        __syncthreads();
        if (changed == 0) break;
    }
    __syncthreads();
    // presence bitmap of roots
    for (int i = t; i < N_EP; i += 1024) rnk[i] = 0;
    __syncthreads();
    for (int i = t; i < N_EP; i += 1024) rnk[lab[i]] = 1;
    __syncthreads();
    // exclusive scan (wave shfl-scan + 16 wave-sums)
    int base = t * 4;
    int a0 = rnk[base], a1 = rnk[base + 1], a2 = rnk[base + 2], a3 = rnk[base + 3];
    int s = a0 + a1 + a2 + a3;
    int lane = t & 63, wv = t >> 6;
    int v = s;
    for (int off = 1; off < 64; off <<= 1) {
        int u = __shfl_up(v, off);
        if (lane >= off) v += u;
    }
    if (lane == 63) wsum[wv] = v;
    __syncthreads();
    if (wv == 0 && lane < 16) {
        int w = wsum[lane];
        for (int off = 1; off < 16; off <<= 1) {
            int u = __shfl_up(w, off);
            if (lane >= off) w += u;
        }
        wsum[lane] = w;
    }
    __syncthreads();
    int excl = ((wv == 0) ? 0 : wsum[wv - 1]) + v - s;
    rnk[base] = excl;
    rnk[base + 1] = excl + a0;
    rnk[base + 2] = excl + a0 + a1;
    rnk[base + 3] = excl + a0 + a1 + a2;
    __syncthreads();
    // cluster ids + LDS segment sums
    for (int i = t; i < N_EP; i += 1024) {
        int c = rnk[lab[i]];
        out_lji[i] = (float)c;
        float2 p = ep[i];
        atomicAdd(&fcnt[c], 1.f);
        atomicAdd(&fsx[c], p.x);
        atomicAdd(&fsy[c], p.y);
        atomicAdd(&fss[c], ws_ls[i >> 1]);
        lab[i] = c;                     // lab now holds cluster id
    }
    __syncthreads();
    // segment means -> junction outputs; stash means back into fsx/fsy
    for (int j = t; j < N_EP; j += 1024) {
        float cm = fmaxf(fcnt[j], 1.f);
        float jx = fsx[j] / cm, jy = fsy[j] / cm;
        fsx[j] = jx; fsy[j] = jy;
        junc[2 * j] = jx; junc[2 * j + 1] = jy;
        out_pts[2 * j] = jx; out_pts[2 * j + 1] = jy;
        out_sc[j] = fss[j] / cm;
    }
    __syncthreads();
    // new_lines = junctions[clusters]
    for (int e = t; e < N_EP; e += 1024) {
        int c = lab[e];
        out_nl[2 * e] = fsx[c];
        out_nl[2 * e + 1] = fsy[c];
    }
}

// ============================================================================
// K_C: bilinear sample, one block per channel, plane staged in LDS (input read
// exactly once). Per-block rotated m-window decorrelates norm atomics.
// ============================================================================
__global__ __launch_bounds__(256) void k_samp1(const float* __restrict__ ad,
                                               const float* __restrict__ junc,
                                               float* __restrict__ v_ws,
                                               float* __restrict__ norm) {
    __shared__ float plane[HC_ * WC_];   // 64 KB
    int c = blockIdx.x, t = threadIdx.x;
    const float4* s4 = (const float4*)(ad + c * (HC_ * WC_));
    float4* p4 = (float4*)plane;
    #pragma unroll 4
    for (int i = t; i < HC_ * WC_ / 4; i += 256) p4[i] = s4[i];
    __syncthreads();
    int rot = c * 16;
    for (int k = 0; k < 16; ++k) {
        int m = (t + k * 256 + rot) & (N_EP - 1);
        float px = junc[2 * m], py = junc[2 * m + 1];
        float gx = (px - 3.5f) / 1019.5f * 2.f - 1.f;
        float gy = (py - 3.5f) / 1019.5f * 2.f - 1.f;
        float x = (gx + 1.f) * 0.5f * (WC_ - 1);
        float y = (gy + 1.f) * 0.5f * (HC_ - 1);
        float x0f = fminf(fmaxf(floorf(x), 0.f), WC_ - 1);
        float y0f = fminf(fmaxf(floorf(y), 0.f), HC_ - 1);
        float x1f = fminf(x0f + 1.f, WC_ - 1);
        float y1f = fminf(y0f + 1.f, HC_ - 1);
        float wx = x - x0f, wy = y - y0f;
        int x0 = (int)x0f, x1 = (int)x1f, y0 = (int)y0f, y1 = (int)y1f;
        float v = plane[y0 * WC_ + x0] * (1.f - wx) * (1.f - wy)
                + plane[y0 * WC_ + x1] * wx * (1.f - wy)
                + plane[y1 * WC_ + x0] * (1.f - wx) * wy
                + plane[y1 * WC_ + x1] * wx * wy;
        v_ws[c * N_EP + m] = v;
        atomicAdd(&norm[m], v * v);
    }
}

// ============================================================================
// K_D epilogue: normalize junction descs + masked keypoint descs, fully
// coalesced single pass over all 256*6144 output elements.
// ============================================================================
__global__ __launch_bounds__(256) void k_epi(const float* __restrict__ v_ws,
                                             const float* __restrict__ norm,
                                             const float* __restrict__ desc,
                                             const int* __restrict__ keep,
                                             float* __restrict__ out_desc) {
    int idx = blockIdx.x * 256 + threadIdx.x;      // c*6144 + p
    int c = idx / NPTS_ALL;
    int p = idx - c * NPTS_ALL;
    float o;
    if (p < N_EP) {
        float inv = 1.f / fmaxf(sqrtf(norm[p]), 1e-12f);
        o = v_ws[c * N_EP + p] * inv;
    } else {
        int k = p - N_EP;
        o = keep[k] ? desc[c * KPTS + k] : 0.f;
    }
    out_desc[idx] = o;
}

extern "C" void kernel_launch(void* const* d_in, const int* in_sizes, int n_in,
                              void* d_out, int out_size, void* d_ws, size_t ws_size,
                              hipStream_t stream) {
    const float* lines    = (const float*)d_in[0];   // (1,2048,2,2) == endpoints (4096,2)
    const float* lscores  = (const float*)d_in[1];   // (1,2048)
    const float* kpts     = (const float*)d_in[2];   // (1,2048,2)
    const float* kscores  = (const float*)d_in[3];   // (1,2048)
    const float* descs    = (const float*)d_in[4];   // (1,256,2048)
    const float* alldesc  = (const float*)d_in[5];   // (1,256,128,128)
    float* out = (float*)d_out;

    float* wf = (float*)d_ws;
    int*   wi = (int*)d_ws;

    float* ws_ls  = wf + W_LS;
    int*   deg    = wi + W_DEG;
    int*   nbr    = wi + W_NBR;
    int*   keep   = wi + W_KEEP;
    float* junc   = wf + W_JUNC;
    float* norm   = wf + W_NORM;
    float* v_ws   = wf + W_V;

    k_front<<<N_EP + KPTS + 2, 256, 0, stream>>>(
        (const float2*)lines, (const float2*)kpts, kscores, lscores,
        deg, nbr, keep, ws_ls, norm, out + O_PTS, out + O_SC, out + O_LS);

    size_t lds_bytes = (size_t)(6 * N_EP + 16) * sizeof(int);   // ~96.1 KB
    k_cluster<<<1, 1024, lds_bytes, stream>>>(
        (const float2*)lines, deg, nbr, ws_ls, junc,
        out + O_PTS, out + O_SC, out + O_NL, out + O_LJI);

    k_samp1<<<CCH, 256, 0, stream>>>(alldesc, junc, v_ws, norm);

    k_epi<<<(CCH * NPTS_ALL) / 256, 256, 0, stream>>>(v_ws, norm, descs, keep,
                                                      out + O_DESC);
}